// Round 1
// baseline (18764.792 us; speedup 1.0000x reference)
//
#include <hip/hip_runtime.h>

// Problem constants
#define B_ 64
#define S_ 512
#define I_ 1024
#define H_ 1024

// Phase-2 partitioning: 4 groups x 16 batches; 64 blocks/group x 16 cols
#define G_   4
#define BGB  16   // batches per group
#define NGB  64   // blocks per group
#define NC   16   // columns per block

typedef __attribute__((ext_vector_type(8))) short short8;
typedef __attribute__((ext_vector_type(4))) float f32x4;

// Persistent state in the .so (avoids relying on ws_size)
__device__ __attribute__((aligned(16))) unsigned short g_hbuf[2][B_ * H_];
__device__ unsigned int g_arrive[S_ * G_];

__device__ __forceinline__ short f2bf(float f) {
    unsigned u = __float_as_uint(f);
    unsigned r = (u + 0x7FFFu + ((u >> 16) & 1u)) >> 16;
    return (short)r;
}

// ---------------- init: h0 -> bf16 buffer, zero barrier counters ----------------
__global__ void rnn_init(const float* __restrict__ h0) {
    int i = blockIdx.x * 256 + threadIdx.x;
    if (i < B_ * H_) g_hbuf[0][i] = (unsigned short)f2bf(h0[i]);
    if (i < S_ * G_) g_arrive[i] = 0u;
}

// ---------------- phase 1: xp = X @ Wih^T + bih + bhh  (into d_out, [B,S,H]) ----------------
__global__ __launch_bounds__(256) void rnn_proj(
    const float* __restrict__ X,    // [32768, 1024]
    const float* __restrict__ Wih,  // [1024, 1024]  (row = output col n, inner = k)
    const float* __restrict__ bih,
    const float* __restrict__ bhh,
    float* __restrict__ out)        // [32768, 1024]
{
    __shared__ short As[64][72];  // [m][k], pad 8 shorts keeps 16B align + kills conflicts
    __shared__ short Bs[64][72];  // [n][k]

    const int tid  = threadIdx.x;
    const int bn   = blockIdx.x;   // 0..15
    const int bm   = blockIdx.y;   // 0..511
    const int lane = tid & 63;
    const int w    = tid >> 6;
    const int wm   = w & 1, wn = w >> 1;
    const int quad = lane >> 4, bl = lane & 15;
    const int r0   = tid >> 4, c4 = tid & 15;

    f32x4 acc[2][2] = {};

    for (int kt = 0; kt < 16; ++kt) {
        const int k0 = kt * 64;
#pragma unroll
        for (int rr = 0; rr < 4; ++rr) {
            int r = r0 + rr * 16;
            float4 va = *(const float4*)(X   + (size_t)(bm * 64 + r) * I_ + k0 + c4 * 4);
            float4 vb = *(const float4*)(Wih + (size_t)(bn * 64 + r) * I_ + k0 + c4 * 4);
            As[r][c4 * 4 + 0] = f2bf(va.x);
            As[r][c4 * 4 + 1] = f2bf(va.y);
            As[r][c4 * 4 + 2] = f2bf(va.z);
            As[r][c4 * 4 + 3] = f2bf(va.w);
            Bs[r][c4 * 4 + 0] = f2bf(vb.x);
            Bs[r][c4 * 4 + 1] = f2bf(vb.y);
            Bs[r][c4 * 4 + 2] = f2bf(vb.z);
            Bs[r][c4 * 4 + 3] = f2bf(vb.w);
        }
        __syncthreads();
#pragma unroll
        for (int ks = 0; ks < 2; ++ks) {
            const int kk = ks * 32 + quad * 8;
            short8 a0 = *(const short8*)&As[wm * 32 + bl][kk];
            short8 a1 = *(const short8*)&As[wm * 32 + 16 + bl][kk];
            short8 b0 = *(const short8*)&Bs[wn * 32 + bl][kk];
            short8 b1 = *(const short8*)&Bs[wn * 32 + 16 + bl][kk];
            acc[0][0] = __builtin_amdgcn_mfma_f32_16x16x32_bf16(a0, b0, acc[0][0], 0, 0, 0);
            acc[0][1] = __builtin_amdgcn_mfma_f32_16x16x32_bf16(a0, b1, acc[0][1], 0, 0, 0);
            acc[1][0] = __builtin_amdgcn_mfma_f32_16x16x32_bf16(a1, b0, acc[1][0], 0, 0, 0);
            acc[1][1] = __builtin_amdgcn_mfma_f32_16x16x32_bf16(a1, b1, acc[1][1], 0, 0, 0);
        }
        __syncthreads();
    }

#pragma unroll
    for (int ni = 0; ni < 2; ++ni) {
        int n = bn * 64 + wn * 32 + ni * 16 + bl;
        float bias = bih[n] + bhh[n];
#pragma unroll
        for (int mi = 0; mi < 2; ++mi) {
#pragma unroll
            for (int r = 0; r < 4; ++r) {
                int m = bm * 64 + wm * 32 + mi * 16 + quad * 4 + r;
                out[(size_t)m * H_ + n] = acc[mi][ni][r] + bias;
            }
        }
    }
}

// ---------------- phase 2: 512 sequential steps, persistent blocks ----------------
// block -> (group g, column slice c0..c0+15). W_hh slice lives in LDS for the whole kernel.
__global__ __launch_bounds__(256) void rnn_step(
    const float* __restrict__ Whh,  // [1024, 1024] (row = output col, inner = k)
    float* __restrict__ out)        // [B,S,H] xp in / h out, + h_last at offset B*S*H
{
    __shared__ short Ws[NC][H_ + 8];   // [c][k]
    __shared__ float Cred[4][256];

    const int tid = threadIdx.x;
    const int g   = blockIdx.x & 3;        // group: same (idx mod 8) pairs -> XCD locality
    const int j   = blockIdx.x >> 2;       // 0..63 column-slice index
    const int c0  = j * NC;

    // stage W_hh slice -> LDS bf16
    {
        const int r  = tid >> 4;   // 0..15
        const int c4 = tid & 15;   // 0..15
        const float* wr = Whh + (size_t)(c0 + r) * H_;
#pragma unroll
        for (int i = 0; i < 16; ++i) {
            int k = c4 * 4 + i * 64;
            float4 v = *(const float4*)(wr + k);
            Ws[r][k + 0] = f2bf(v.x);
            Ws[r][k + 1] = f2bf(v.y);
            Ws[r][k + 2] = f2bf(v.z);
            Ws[r][k + 3] = f2bf(v.w);
        }
    }
    __syncthreads();

    const int w    = tid >> 6;      // wave 0..3: K range [w*256, w*256+256)
    const int lane = tid & 63;
    const int quad = lane >> 4;
    const int bl   = lane & 15;
    const int em   = tid >> 4;      // epilogue m (batch-local) 0..15
    const int en   = tid & 15;      // epilogue n (col-local)   0..15
    const int brow = g * BGB;

    const unsigned short* __restrict__ harow = g_hbuf[0]; // base; indexed with cur below

    float xp_cur = out[((size_t)(brow + em) * S_ + 0) * H_ + c0 + en];

    for (int t = 0; t < S_; ++t) {
        // prefetch next xp (independent of barrier)
        float xp_next = 0.f;
        if (t + 1 < S_)
            xp_next = out[((size_t)(brow + em) * S_ + (t + 1)) * H_ + c0 + en];

        if (t > 0) {
            if (tid == 0) {
                while (__hip_atomic_load(&g_arrive[(t - 1) * G_ + g],
                                         __ATOMIC_RELAXED, __HIP_MEMORY_SCOPE_AGENT) < NGB)
                    __builtin_amdgcn_s_sleep(1);
            }
            __syncthreads();
            // every thread acquires once: orders + invalidates stale cached h lines
            (void)__hip_atomic_load(&g_arrive[(t - 1) * G_ + g],
                                    __ATOMIC_ACQUIRE, __HIP_MEMORY_SCOPE_AGENT);
        }

        const int cur = t & 1;
        const unsigned short* hb = g_hbuf[cur] + (size_t)(brow + bl) * H_;

        f32x4 acc = {0.f, 0.f, 0.f, 0.f};
#pragma unroll
        for (int i = 0; i < 8; ++i) {
            int k = w * 256 + i * 32 + quad * 8;
            short8 a = *(const short8*)(hb + k);          // A[m=bl][k]
            short8 b = *(const short8*)(&Ws[bl][k]);      // B[k][n=bl]
            acc = __builtin_amdgcn_mfma_f32_16x16x32_bf16(a, b, acc, 0, 0, 0);
        }

#pragma unroll
        for (int r = 0; r < 4; ++r)
            Cred[w][(quad * 4 + r) * 16 + bl] = acc[r];
        __syncthreads();

        float v = Cred[0][tid] + Cred[1][tid] + Cred[2][tid] + Cred[3][tid] + xp_cur;
        v = fmaxf(v, 0.f);
        out[((size_t)(brow + em) * S_ + t) * H_ + c0 + en] = v;
        g_hbuf[1 - cur][(size_t)(brow + em) * H_ + c0 + en] = (unsigned short)f2bf(v);
        if (t == S_ - 1)
            out[(size_t)B_ * S_ * H_ + (size_t)(brow + em) * H_ + c0 + en] = v;

        __threadfence();
        __syncthreads();
        if (tid == 0)
            __hip_atomic_fetch_add(&g_arrive[t * G_ + g], 1u,
                                   __ATOMIC_RELEASE, __HIP_MEMORY_SCOPE_AGENT);

        xp_cur = xp_next;
    }
    (void)harow;
}

extern "C" void kernel_launch(void* const* d_in, const int* in_sizes, int n_in,
                              void* d_out, int out_size, void* d_ws, size_t ws_size,
                              hipStream_t stream) {
    const float* X    = (const float*)d_in[0];  // [B,S,I]
    const float* h0   = (const float*)d_in[1];  // [1,B,H]
    const float* Wih  = (const float*)d_in[2];  // [H,I]
    const float* Whh  = (const float*)d_in[3];  // [H,H]
    const float* bih  = (const float*)d_in[4];  // [H]
    const float* bhh  = (const float*)d_in[5];  // [H]
    float* out = (float*)d_out;

    rnn_init<<<256, 256, 0, stream>>>(h0);
    rnn_proj<<<dim3(16, 512), 256, 0, stream>>>(X, Wih, bih, bhh, out);
    rnn_step<<<256, 256, 0, stream>>>(Whh, out);
}

// Round 2
// 5010.757 us; speedup vs baseline: 3.7449x; 3.7449x over previous
//
#include <hip/hip_runtime.h>

// Problem constants
#define B_ 64
#define S_ 512
#define I_ 1024
#define H_ 1024

// Phase-2 partitioning: 4 groups x 16 batches; 64 blocks/group x 16 cols
#define G_   4
#define BGB  16   // batches per group
#define NGB  64   // blocks per group
#define NC   16   // columns per block

typedef __attribute__((ext_vector_type(8))) short short8;
typedef __attribute__((ext_vector_type(4))) float f32x4;

// Persistent state in the .so (avoids relying on ws_size)
__device__ __attribute__((aligned(16))) unsigned short g_hbuf[2][B_ * H_];
__device__ unsigned int g_arrive[S_ * G_];

__device__ __forceinline__ short f2bf(float f) {
    unsigned u = __float_as_uint(f);
    unsigned r = (u + 0x7FFFu + ((u >> 16) & 1u)) >> 16;
    return (short)r;
}

// ---------------- init: h0 -> bf16 buffer, zero barrier counters ----------------
__global__ void rnn_init(const float* __restrict__ h0) {
    int i = blockIdx.x * 256 + threadIdx.x;
    if (i < B_ * H_) g_hbuf[0][i] = (unsigned short)f2bf(h0[i]);
    if (i < S_ * G_) g_arrive[i] = 0u;
}

// ---------------- phase 1: xp = X @ Wih^T + bih + bhh  (into d_out, [B,S,H]) ----------------
__global__ __launch_bounds__(256) void rnn_proj(
    const float* __restrict__ X,    // [32768, 1024]
    const float* __restrict__ Wih,  // [1024, 1024]  (row = output col n, inner = k)
    const float* __restrict__ bih,
    const float* __restrict__ bhh,
    float* __restrict__ out)        // [32768, 1024]
{
    __shared__ short As[64][72];  // [m][k], pad 8 shorts keeps 16B align + kills conflicts
    __shared__ short Bs[64][72];  // [n][k]

    const int tid  = threadIdx.x;
    const int bn   = blockIdx.x;   // 0..15
    const int bm   = blockIdx.y;   // 0..511
    const int lane = tid & 63;
    const int w    = tid >> 6;
    const int wm   = w & 1, wn = w >> 1;
    const int quad = lane >> 4, bl = lane & 15;
    const int r0   = tid >> 4, c4 = tid & 15;

    f32x4 acc[2][2] = {};

    for (int kt = 0; kt < 16; ++kt) {
        const int k0 = kt * 64;
#pragma unroll
        for (int rr = 0; rr < 4; ++rr) {
            int r = r0 + rr * 16;
            float4 va = *(const float4*)(X   + (size_t)(bm * 64 + r) * I_ + k0 + c4 * 4);
            float4 vb = *(const float4*)(Wih + (size_t)(bn * 64 + r) * I_ + k0 + c4 * 4);
            As[r][c4 * 4 + 0] = f2bf(va.x);
            As[r][c4 * 4 + 1] = f2bf(va.y);
            As[r][c4 * 4 + 2] = f2bf(va.z);
            As[r][c4 * 4 + 3] = f2bf(va.w);
            Bs[r][c4 * 4 + 0] = f2bf(vb.x);
            Bs[r][c4 * 4 + 1] = f2bf(vb.y);
            Bs[r][c4 * 4 + 2] = f2bf(vb.z);
            Bs[r][c4 * 4 + 3] = f2bf(vb.w);
        }
        __syncthreads();
#pragma unroll
        for (int ks = 0; ks < 2; ++ks) {
            const int kk = ks * 32 + quad * 8;
            short8 a0 = *(const short8*)&As[wm * 32 + bl][kk];
            short8 a1 = *(const short8*)&As[wm * 32 + 16 + bl][kk];
            short8 b0 = *(const short8*)&Bs[wn * 32 + bl][kk];
            short8 b1 = *(const short8*)&Bs[wn * 32 + 16 + bl][kk];
            acc[0][0] = __builtin_amdgcn_mfma_f32_16x16x32_bf16(a0, b0, acc[0][0], 0, 0, 0);
            acc[0][1] = __builtin_amdgcn_mfma_f32_16x16x32_bf16(a0, b1, acc[0][1], 0, 0, 0);
            acc[1][0] = __builtin_amdgcn_mfma_f32_16x16x32_bf16(a1, b0, acc[1][0], 0, 0, 0);
            acc[1][1] = __builtin_amdgcn_mfma_f32_16x16x32_bf16(a1, b1, acc[1][1], 0, 0, 0);
        }
        __syncthreads();
    }

#pragma unroll
    for (int ni = 0; ni < 2; ++ni) {
        int n = bn * 64 + wn * 32 + ni * 16 + bl;
        float bias = bih[n] + bhh[n];
#pragma unroll
        for (int mi = 0; mi < 2; ++mi) {
#pragma unroll
            for (int r = 0; r < 4; ++r) {
                int m = bm * 64 + wm * 32 + mi * 16 + quad * 4 + r;
                out[(size_t)m * H_ + n] = acc[mi][ni][r] + bias;
            }
        }
    }
}

// ---------------- phase 2: 512 sequential steps, persistent blocks ----------------
// block -> (group g, column slice c0..c0+15). W_hh slice lives in LDS for the whole kernel.
// Barrier protocol: exactly ONE agent-scope release op and ONE agent-scope acquire op
// per block per step (tid 0 only). __syncthreads drains every wave's vmcnt first, so
// tid 0's release fence (buffer_wbl2) covers all waves' stores; tid 0's acquire inv
// covers the CU-shared L1 for all waves.
__global__ __launch_bounds__(256) void rnn_step(
    const float* __restrict__ Whh,  // [1024, 1024] (row = output col, inner = k)
    float* __restrict__ out)        // [B,S,H] xp in / h out, + h_last at offset B*S*H
{
    __shared__ short Ws[NC][H_ + 8];   // [c][k]
    __shared__ float Cred[4][256];

    const int tid = threadIdx.x;
    const int g   = blockIdx.x & 3;        // group: same (idx mod 8) pairs -> XCD locality
    const int j   = blockIdx.x >> 2;       // 0..63 column-slice index
    const int c0  = j * NC;

    // stage W_hh slice -> LDS bf16
    {
        const int r  = tid >> 4;   // 0..15
        const int c4 = tid & 15;   // 0..15
        const float* wr = Whh + (size_t)(c0 + r) * H_;
#pragma unroll
        for (int i = 0; i < 16; ++i) {
            int k = c4 * 4 + i * 64;
            float4 v = *(const float4*)(wr + k);
            Ws[r][k + 0] = f2bf(v.x);
            Ws[r][k + 1] = f2bf(v.y);
            Ws[r][k + 2] = f2bf(v.z);
            Ws[r][k + 3] = f2bf(v.w);
        }
    }
    __syncthreads();

    const int w    = tid >> 6;      // wave 0..3: K range [w*256, w*256+256)
    const int lane = tid & 63;
    const int quad = lane >> 4;
    const int bl   = lane & 15;
    const int em   = tid >> 4;      // epilogue m (batch-local) 0..15
    const int en   = tid & 15;      // epilogue n (col-local)   0..15
    const int brow = g * BGB;

    float xp_cur = out[((size_t)(brow + em) * S_ + 0) * H_ + c0 + en];

    for (int t = 0; t < S_; ++t) {
        // prefetch next xp (independent of barrier)
        float xp_next = 0.f;
        if (t + 1 < S_)
            xp_next = out[((size_t)(brow + em) * S_ + (t + 1)) * H_ + c0 + en];

        if (t > 0) {
            if (tid == 0) {
                while (__hip_atomic_load(&g_arrive[(t - 1) * G_ + g],
                                         __ATOMIC_RELAXED, __HIP_MEMORY_SCOPE_AGENT) < NGB)
                    __builtin_amdgcn_s_sleep(1);
                // single acquire: orders + invalidates stale L1 (CU-shared) / L2 lines
                (void)__hip_atomic_load(&g_arrive[(t - 1) * G_ + g],
                                        __ATOMIC_ACQUIRE, __HIP_MEMORY_SCOPE_AGENT);
            }
            __syncthreads();
        }

        const int cur = t & 1;
        const unsigned short* hb = g_hbuf[cur] + (size_t)(brow + bl) * H_;

        f32x4 acc = {0.f, 0.f, 0.f, 0.f};
#pragma unroll
        for (int i = 0; i < 8; ++i) {
            int k = w * 256 + i * 32 + quad * 8;
            short8 a = *(const short8*)(hb + k);          // A[m=bl][k]
            short8 b = *(const short8*)(&Ws[bl][k]);      // B[k][n=bl]
            acc = __builtin_amdgcn_mfma_f32_16x16x32_bf16(a, b, acc, 0, 0, 0);
        }

#pragma unroll
        for (int r = 0; r < 4; ++r)
            Cred[w][(quad * 4 + r) * 16 + bl] = acc[r];
        __syncthreads();

        float v = Cred[0][tid] + Cred[1][tid] + Cred[2][tid] + Cred[3][tid] + xp_cur;
        v = fmaxf(v, 0.f);
        out[((size_t)(brow + em) * S_ + t) * H_ + c0 + en] = v;
        g_hbuf[1 - cur][(size_t)(brow + em) * H_ + c0 + en] = (unsigned short)f2bf(v);
        if (t == S_ - 1)
            out[(size_t)B_ * S_ * H_ + (size_t)(brow + em) * H_ + c0 + en] = v;

        // all waves drain vmcnt at this barrier -> block's stores are in (write-through)
        // L1/L2; then tid 0's RELEASE fence writes back the XCD L2 once for the block.
        __syncthreads();
        if (tid == 0)
            __hip_atomic_fetch_add(&g_arrive[t * G_ + g], 1u,
                                   __ATOMIC_RELEASE, __HIP_MEMORY_SCOPE_AGENT);

        xp_cur = xp_next;
    }
}

extern "C" void kernel_launch(void* const* d_in, const int* in_sizes, int n_in,
                              void* d_out, int out_size, void* d_ws, size_t ws_size,
                              hipStream_t stream) {
    const float* X    = (const float*)d_in[0];  // [B,S,I]
    const float* h0   = (const float*)d_in[1];  // [1,B,H]
    const float* Wih  = (const float*)d_in[2];  // [H,I]
    const float* Whh  = (const float*)d_in[3];  // [H,H]
    const float* bih  = (const float*)d_in[4];  // [H]
    const float* bhh  = (const float*)d_in[5];  // [H]
    float* out = (float*)d_out;

    rnn_init<<<256, 256, 0, stream>>>(h0);
    rnn_proj<<<dim3(16, 512), 256, 0, stream>>>(X, Wih, bih, bhh, out);
    rnn_step<<<256, 256, 0, stream>>>(Whh, out);
}

// Round 4
// 2459.130 us; speedup vs baseline: 7.6307x; 2.0376x over previous
//
#include <hip/hip_runtime.h>

// Problem constants
#define B_ 64
#define S_ 512
#define I_ 1024
#define H_ 1024

// Phase-2 partitioning: 4 groups x 16 batches; 16 blocks/group x 64 cols
#define G_   4
#define BGB  16   // batches per group
#define NGB  16   // blocks per group
#define NC   64   // columns per block

typedef __attribute__((ext_vector_type(8))) short short8;
typedef __attribute__((ext_vector_type(4))) float f32x4;

// Persistent state in the .so. h buffers typed as u64 so 8-byte agent-scope
// atomics have provable alignment (each u64 = 4 bf16 values).
__device__ __attribute__((aligned(16))) unsigned long long g_hbuf[2][B_ * H_ / 4];
__device__ __attribute__((aligned(64))) unsigned int g_flag[G_ * NGB];

__device__ __forceinline__ short f2bf(float f) {
    unsigned u = __float_as_uint(f);
    unsigned r = (u + 0x7FFFu + ((u >> 16) & 1u)) >> 16;
    return (short)r;
}

// ---------------- init: h0 -> bf16 buffer, zero flags ----------------
__global__ void rnn_init(const float* __restrict__ h0) {
    int i = blockIdx.x * 256 + threadIdx.x;  // u64 index, 4 floats each
    if (i < B_ * H_ / 4) {
        float4 v = *(const float4*)(h0 + i * 4);
        unsigned long long hp =
              (unsigned long long)(unsigned short)f2bf(v.x)
            | ((unsigned long long)(unsigned short)f2bf(v.y) << 16)
            | ((unsigned long long)(unsigned short)f2bf(v.z) << 32)
            | ((unsigned long long)(unsigned short)f2bf(v.w) << 48);
        g_hbuf[0][i] = hp;
    }
    if (i < G_ * NGB) g_flag[i] = 0u;
}

// ---------------- phase 1: xp = X @ Wih^T + bih + bhh  (into d_out, [B,S,H]) ----------------
__global__ __launch_bounds__(256) void rnn_proj(
    const float* __restrict__ X,    // [32768, 1024]
    const float* __restrict__ Wih,  // [1024, 1024]  (row = output col n, inner = k)
    const float* __restrict__ bih,
    const float* __restrict__ bhh,
    float* __restrict__ out)        // [32768, 1024]
{
    __shared__ short As[64][72];
    __shared__ short Bs[64][72];

    const int tid  = threadIdx.x;
    const int bn   = blockIdx.x;   // 0..15
    const int bm   = blockIdx.y;   // 0..511
    const int lane = tid & 63;
    const int w    = tid >> 6;
    const int wm   = w & 1, wn = w >> 1;
    const int quad = lane >> 4, bl = lane & 15;
    const int r0   = tid >> 4, c4 = tid & 15;

    f32x4 acc[2][2] = {};

    for (int kt = 0; kt < 16; ++kt) {
        const int k0 = kt * 64;
#pragma unroll
        for (int rr = 0; rr < 4; ++rr) {
            int r = r0 + rr * 16;
            float4 va = *(const float4*)(X   + (size_t)(bm * 64 + r) * I_ + k0 + c4 * 4);
            float4 vb = *(const float4*)(Wih + (size_t)(bn * 64 + r) * I_ + k0 + c4 * 4);
            As[r][c4 * 4 + 0] = f2bf(va.x);
            As[r][c4 * 4 + 1] = f2bf(va.y);
            As[r][c4 * 4 + 2] = f2bf(va.z);
            As[r][c4 * 4 + 3] = f2bf(va.w);
            Bs[r][c4 * 4 + 0] = f2bf(vb.x);
            Bs[r][c4 * 4 + 1] = f2bf(vb.y);
            Bs[r][c4 * 4 + 2] = f2bf(vb.z);
            Bs[r][c4 * 4 + 3] = f2bf(vb.w);
        }
        __syncthreads();
#pragma unroll
        for (int ks = 0; ks < 2; ++ks) {
            const int kk = ks * 32 + quad * 8;
            short8 a0 = *(const short8*)&As[wm * 32 + bl][kk];
            short8 a1 = *(const short8*)&As[wm * 32 + 16 + bl][kk];
            short8 b0 = *(const short8*)&Bs[wn * 32 + bl][kk];
            short8 b1 = *(const short8*)&Bs[wn * 32 + 16 + bl][kk];
            acc[0][0] = __builtin_amdgcn_mfma_f32_16x16x32_bf16(a0, b0, acc[0][0], 0, 0, 0);
            acc[0][1] = __builtin_amdgcn_mfma_f32_16x16x32_bf16(a0, b1, acc[0][1], 0, 0, 0);
            acc[1][0] = __builtin_amdgcn_mfma_f32_16x16x32_bf16(a1, b0, acc[1][0], 0, 0, 0);
            acc[1][1] = __builtin_amdgcn_mfma_f32_16x16x32_bf16(a1, b1, acc[1][1], 0, 0, 0);
        }
        __syncthreads();
    }

#pragma unroll
    for (int ni = 0; ni < 2; ++ni) {
        int n = bn * 64 + wn * 32 + ni * 16 + bl;
        float bias = bih[n] + bhh[n];
#pragma unroll
        for (int mi = 0; mi < 2; ++mi) {
#pragma unroll
            for (int r = 0; r < 4; ++r) {
                int m = bm * 64 + wm * 32 + mi * 16 + quad * 4 + r;
                out[(size_t)m * H_ + n] = acc[mi][ni][r] + bias;
            }
        }
    }
}

// ---------------- phase 2: 512 sequential steps, persistent blocks ----------------
// All inter-block h traffic uses relaxed AGENT-scope atomics (bypass the
// non-coherent L1/L2, hit the L3 coherence point directly) -> no buffer_wbl2 /
// buffer_inv cache walks anywhere. Ordering: h stores -> s_waitcnt vmcnt(0) +
// __syncthreads -> tid0 writes this block's flag word (no atomic RMW). Consumers
// poll the 16 flag words (one thread each), then __syncthreads, then h loads.
__global__ __launch_bounds__(256, 1) void rnn_step(
    const float* __restrict__ Whh,  // [1024, 1024] (row = output col, inner = k)
    float* __restrict__ out)        // [B,S,H] xp in / h out, + h_last at offset B*S*H
{
    __shared__ float Cred[4][16][68];   // [wave][m][n], stride 68 -> 2-way max

    const int tid = threadIdx.x;
    const int g   = blockIdx.x >> 4;   // 0..3  group
    const int j   = blockIdx.x & 15;   // 0..15 column-slice index
    const int c0  = j * NC;

    const int w    = tid >> 6;      // wave 0..3: K range [w*256, w*256+256)
    const int lane = tid & 63;
    const int quad = lane >> 4;
    const int bl   = lane & 15;
    const int em   = tid >> 4;      // epilogue m (batch-local) 0..15
    const int en4  = (tid & 15) * 4;// epilogue n (col-local), 4 consecutive
    const int brow = g * BGB;

    // ---- prologue: W_hh fragments -> registers (constant across all 512 steps)
    // wave w holds B[n = c0..c0+63][k = w*256 .. w*256+255] as 32 short8 frags.
    short8 bfrag[4][8];
#pragma unroll
    for (int ni = 0; ni < 4; ++ni) {
        const float* wr = Whh + (size_t)(c0 + ni * 16 + bl) * H_;
#pragma unroll
        for (int kk = 0; kk < 8; ++kk) {
            int k = w * 256 + kk * 32 + quad * 8;
            float4 x = *(const float4*)(wr + k);
            float4 y = *(const float4*)(wr + k + 4);
            short8 b;
            b[0] = f2bf(x.x); b[1] = f2bf(x.y); b[2] = f2bf(x.z); b[3] = f2bf(x.w);
            b[4] = f2bf(y.x); b[5] = f2bf(y.y); b[6] = f2bf(y.z); b[7] = f2bf(y.w);
            bfrag[ni][kk] = b;
        }
    }

    float4 xp_cur = *(const float4*)(out + ((size_t)(brow + em) * S_ + 0) * H_ + c0 + en4);

    for (int t = 0; t < S_; ++t) {
        // prefetch next xp (independent of the flag wait)
        float4 xp_next = {0.f, 0.f, 0.f, 0.f};
        if (t + 1 < S_)
            xp_next = *(const float4*)(out + ((size_t)(brow + em) * S_ + (t + 1)) * H_ + c0 + en4);

        if (t > 0) {
            if (tid < NGB) {
                while (__hip_atomic_load(&g_flag[g * NGB + tid],
                                         __ATOMIC_RELAXED, __HIP_MEMORY_SCOPE_AGENT) < (unsigned)t)
                    __builtin_amdgcn_s_sleep(1);
            }
            __syncthreads();
        }

        const int cur = t & 1;
        // u64 index of A-row (batch brow+bl), this wave's K slice, this quad's 8-elem chunk
        const unsigned long long* hb =
            g_hbuf[cur] + (size_t)(brow + bl) * (H_ / 4) + w * 64 + quad * 2;

        f32x4 acc[4] = {{0,0,0,0},{0,0,0,0},{0,0,0,0},{0,0,0,0}};
#pragma unroll
        for (int i = 0; i < 8; ++i) {
            union { unsigned long long u[2]; short8 s; } a;
            const unsigned long long* p = hb + i * 8;   // +32 shorts per K-step
            a.u[0] = __hip_atomic_load(p,     __ATOMIC_RELAXED, __HIP_MEMORY_SCOPE_AGENT);
            a.u[1] = __hip_atomic_load(p + 1, __ATOMIC_RELAXED, __HIP_MEMORY_SCOPE_AGENT);
#pragma unroll
            for (int ni = 0; ni < 4; ++ni)
                acc[ni] = __builtin_amdgcn_mfma_f32_16x16x32_bf16(a.s, bfrag[ni][i], acc[ni], 0, 0, 0);
        }

        // cross-wave K reduction through LDS
#pragma unroll
        for (int ni = 0; ni < 4; ++ni)
#pragma unroll
            for (int r = 0; r < 4; ++r)
                Cred[w][quad * 4 + r][ni * 16 + bl] = acc[ni][r];
        __syncthreads();

        float4 sv = {0.f, 0.f, 0.f, 0.f};
#pragma unroll
        for (int ww = 0; ww < 4; ++ww) {
            float4 c = *(const float4*)&Cred[ww][em][en4];
            sv.x += c.x; sv.y += c.y; sv.z += c.z; sv.w += c.w;
        }
        sv.x = fmaxf(sv.x + xp_cur.x, 0.f);
        sv.y = fmaxf(sv.y + xp_cur.y, 0.f);
        sv.z = fmaxf(sv.z + xp_cur.z, 0.f);
        sv.w = fmaxf(sv.w + xp_cur.w, 0.f);

        *(float4*)(out + ((size_t)(brow + em) * S_ + t) * H_ + c0 + en4) = sv;

        unsigned long long hp =
              (unsigned long long)(unsigned short)f2bf(sv.x)
            | ((unsigned long long)(unsigned short)f2bf(sv.y) << 16)
            | ((unsigned long long)(unsigned short)f2bf(sv.z) << 32)
            | ((unsigned long long)(unsigned short)f2bf(sv.w) << 48);
        __hip_atomic_store(
            g_hbuf[1 - cur] + (size_t)(brow + em) * (H_ / 4) + (c0 + en4) / 4,
            hp, __ATOMIC_RELAXED, __HIP_MEMORY_SCOPE_AGENT);

        if (t == S_ - 1)
            *(float4*)(out + (size_t)B_ * S_ * H_ + (size_t)(brow + em) * H_ + c0 + en4) = sv;

        // guarantee this wave's h stores are complete at the coherence point,
        // then rendezvous all waves, then publish the block's flag.
        asm volatile("s_waitcnt vmcnt(0)" ::: "memory");
        __syncthreads();
        if (tid == 0)
            __hip_atomic_store(&g_flag[g * NGB + j], (unsigned)(t + 1),
                               __ATOMIC_RELAXED, __HIP_MEMORY_SCOPE_AGENT);

        xp_cur = xp_next;
    }
}

extern "C" void kernel_launch(void* const* d_in, const int* in_sizes, int n_in,
                              void* d_out, int out_size, void* d_ws, size_t ws_size,
                              hipStream_t stream) {
    const float* X    = (const float*)d_in[0];  // [B,S,I]
    const float* h0   = (const float*)d_in[1];  // [1,B,H]
    const float* Wih  = (const float*)d_in[2];  // [H,I]
    const float* Whh  = (const float*)d_in[3];  // [H,H]
    const float* bih  = (const float*)d_in[4];  // [H]
    const float* bhh  = (const float*)d_in[5];  // [H]
    float* out = (float*)d_out;

    rnn_init<<<256, 256, 0, stream>>>(h0);
    rnn_proj<<<dim3(16, 512), 256, 0, stream>>>(X, Wih, bih, bhh, out);
    rnn_step<<<64, 256, 0, stream>>>(Whh, out);
}